// Round 3
// baseline (324.694 us; speedup 1.0000x reference)
//
#include <hip/hip_runtime.h>
#include <hip/hip_fp16.h>
#include <math.h>

#define N_NODES 100000
#define N_EDGES 1600000
#define EP (N_EDGES + N_NODES)   // edges incl self-loops
#define HID 64
#define NCHUNK 250                               // scatter chunks (>= 1 block per CU)
#define CE (N_EDGES / NCHUNK)                    // 6400 edges per chunk (exact, /4 ok)
#define NBUCK 782                                // buckets of 128 node-keys (ceil(1e5/128))
#define CAP 2816                                 // fixed ebuf window per bucket (mean 2048, +17 sigma)
#define NTILE (N_NODES / 16)                     // 6250 tiles = blocks (exact)
#define STASH CAP                                // stash covers the whole bucket window
#define OBSTRIDE 512                             // u64 overflow slots per bucket (rank>=128 only)
#define NPN 4                                    // nodes per wave (gather), even
#define GT_NODES 32                              // nodes per gcol block
#define GT_TILES (N_NODES / GT_NODES)            // 3125 (exact)

typedef _Float16 half8_t __attribute__((ext_vector_type(8)));
typedef _Float16 half4_t __attribute__((ext_vector_type(4)));
typedef float f32x4_t __attribute__((ext_vector_type(4)));
typedef unsigned long long u64;

// ================= bucketed CSR build v7 (128-node buckets) =================

__global__ void init_kernel(int* __restrict__ gcur, int* __restrict__ csr) {
    int t = threadIdx.x;
    for (int b = t; b < NBUCK; b += 512) gcur[b] = b * CAP;
    if (t < 64) csr[EP + t] = 0;
}

__global__ __launch_bounds__(1024)
void scatter_kernel(const int* __restrict__ src, const int* __restrict__ dst,
                    int* __restrict__ gcur, unsigned* __restrict__ ebuf) {
    __shared__ int hist[NBUCK];
    __shared__ int cur[NBUCK];
    const int tid = threadIdx.x, c = blockIdx.x;
    for (int b = tid; b < NBUCK; b += 1024) hist[b] = 0;
    __syncthreads();
    const int4* d4p = (const int4*)(dst + c * CE);
    const int4* s4p = (const int4*)(src + c * CE);
    for (int t = tid; t < CE / 4; t += 1024) {
        int4 d = d4p[t];
        atomicAdd(&hist[d.x >> 7], 1);
        atomicAdd(&hist[d.y >> 7], 1);
        atomicAdd(&hist[d.z >> 7], 1);
        atomicAdd(&hist[d.w >> 7], 1);
    }
    __syncthreads();
    for (int b = tid; b < NBUCK; b += 1024)
        cur[b] = hist[b] ? atomicAdd(&gcur[b], hist[b]) : 0;
    __syncthreads();
    for (int t = tid; t < CE / 4; t += 1024) {
        int4 s = s4p[t];
        int4 d = d4p[t];
        int p0 = atomicAdd(&cur[d.x >> 7], 1);
        ebuf[p0] = ((unsigned)(d.x & 127) << 17) | (unsigned)s.x;   // src < 2^17
        int p1 = atomicAdd(&cur[d.y >> 7], 1);
        ebuf[p1] = ((unsigned)(d.y & 127) << 17) | (unsigned)s.y;
        int p2 = atomicAdd(&cur[d.z >> 7], 1);
        ebuf[p2] = ((unsigned)(d.z & 127) << 17) | (unsigned)s.z;
        int p3 = atomicAdd(&cur[d.w >> 7], 1);
        ebuf[p3] = ((unsigned)(d.w & 127) << 17) | (unsigned)s.w;
    }
}

__global__ void bscan_kernel(const int* __restrict__ gcur, int* __restrict__ bR0) {
    __shared__ int tmp[1024];
    int t = threadIdx.x;
    int v = (t < NBUCK) ? (gcur[t] - t * CAP + 128) : 0;
    tmp[t] = v;
    __syncthreads();
    for (int off = 1; off < 1024; off <<= 1) {
        int y = (t >= off) ? tmp[t - off] : 0;
        __syncthreads();
        tmp[t] += y;
        __syncthreads();
    }
    if (t < NBUCK) bR0[t] = tmp[t] - v;   // exclusive prefix
}

__global__ __launch_bounds__(256)
void rankfill_kernel(const unsigned* __restrict__ ebuf, const int* __restrict__ gcur,
                     const int* __restrict__ bR0, u64* __restrict__ obuf,
                     int* __restrict__ rowptr, int* __restrict__ csr,
                     float* __restrict__ dinv,
                     const float* __restrict__ x, float4* __restrict__ xd) {
    __shared__ int cnt[128];
    __shared__ int rpl[128];
    __shared__ int wsum[2];
    __shared__ int ocnt;
    __shared__ unsigned stash[STASH];
    const int tid = threadIdx.x, b = blockIdx.x;
    if (tid < 128) cnt[tid] = 0;
    if (tid == 0) ocnt = 0;
    __syncthreads();
    const int E0 = b * CAP;
    const int RL = gcur[b] - E0;          // bucket edge count (<= CAP = STASH)
    const int R0 = bR0[b];                // global rowptr base for this bucket
    for (int off = tid; off < RL; off += 256) {
        unsigned v = ebuf[E0 + off];
        int key = (v >> 17) & 0x7F;
        int r = atomicAdd(&cnt[key], 1);
        if (r < 128) {
            stash[off] = ((unsigned)r << 24) | v;
        } else {                                      // ~ never (deg >= 128)
            stash[off] = 0xFFFFFFFFu;
            int oi = atomicAdd(&ocnt, 1);
            obuf[(size_t)b * OBSTRIDE + oi] =
                ((u64)r << 40) | ((u64)key << 32) | (u64)(v & 0x1FFFFu);
        }
    }
    __syncthreads();
    const int lane = tid & 63, w = tid >> 6;
    int xcnt = (tid < 128) ? cnt[tid] : 0;
    int inc = xcnt;
#pragma unroll
    for (int off = 1; off < 64; off <<= 1) {
        int y = __shfl_up(inc, off, 64);
        if (lane >= off) inc += y;
    }
    if (lane == 63 && w < 2) wsum[w] = inc;
    __syncthreads();
    if (tid < 128) {
        int base = (w == 1) ? wsum[0] : 0;
        int pre = base + inc - xcnt;
        const int n = b * 128 + tid;
        const int rpn = R0 + tid + pre;   // bucket base + in-bucket self-loops + edge prefix
        rpl[tid] = rpn;
        if (n < N_NODES) {
            rowptr[n] = rpn;
            float di = rsqrtf((float)(xcnt + 1));
            dinv[n] = di;
            csr[rpn + xcnt] = n;          // self-loop at end of node's list
            xd[n] = make_float4(x[n * 3 + 0] * di, x[n * 3 + 1] * di, x[n * 3 + 2] * di, 0.f);
        }
    }
    if (b == NBUCK - 1 && tid == 0) rowptr[N_NODES] = EP;
    __syncthreads();
    for (int off = tid; off < RL; off += 256) {
        unsigned v = stash[off];
        if (v == 0xFFFFFFFFu) continue;
        csr[rpl[(v >> 17) & 0x7F] + (v >> 24)] = (int)(v & 0x1FFFFu);
    }
    for (int j = tid; j < ocnt; j += 256) {             // ~ never
        u64 pk = obuf[(size_t)b * OBSTRIDE + j];
        csr[rpl[(pk >> 32) & 0xFF] + (int)(pk >> 40)] = (int)(pk & 0x1FFFFu);
    }
}

// ================= helpers =================

__device__ __forceinline__ void addp(float4& a, uint2 u, bool pred) {
    __half2 h0 = *(__half2*)&u.x, h1 = *(__half2*)&u.y;
    float2 x = __half22float2(h0), y = __half22float2(h1);
    if (pred) { a.x += x.x; a.y += x.y; a.z += y.x; a.w += y.y; }
}

// ================= column-pass gather (L2-resident 3.2 MB working set) =================
// gfc layout: [4][N][16] fp16 (pass-major column blocks). agg: same layout.
// agg[p][n][:] = relu(dinv[n] * sum_{s in N(n)} gfc[p][s][:] + bias[p*16:...])
// Pass-major blockIdx: dispatch-order monotonicity keeps one pass's 3.2 MB hot in each XCD L2.

__global__ __launch_bounds__(256, 8)
void gcol_kernel(const __half* __restrict__ gfc, const int* __restrict__ rowptr,
                 const int* __restrict__ csr, const float* __restrict__ dinv,
                 const float* __restrict__ bias, __half* __restrict__ agg) {
    const int pass = blockIdx.x / GT_TILES;
    const int tile = blockIdx.x % GT_TILES;
    const int tid = threadIdx.x;
    const int lane = tid & 63, wid = tid >> 6;
    const int r = lane >> 2, c = lane & 3;          // 16 rank-slots x 4 col-u2s
    const uint2* g2 = (const uint2*)gfc + (size_t)pass * N_NODES * 4;
    uint2* a2 = (uint2*)agg + (size_t)pass * N_NODES * 4;
    const float4 bb = ((const float4*)bias)[pass * 4 + c];
    const int nbase = tile * GT_NODES + wid * (GT_NODES / 4);   // 8 nodes per wave
#pragma unroll
    for (int i = 0; i < GT_NODES / 4; i += 2) {
        const int nA = nbase + i, nB = nbase + i + 1;
        const int begA = rowptr[nA], endA = rowptr[nA + 1];
        const int begB = rowptr[nB], endB = rowptr[nB + 1];
        const int cA = endA - begA, cB = endB - begB;
        int iA = (r < cA) ? csr[begA + r] : 0;
        int iB = (r < cB) ? csr[begB + r] : 0;
        uint2 uA = g2[(size_t)iA * 4 + c];
        uint2 uB = g2[(size_t)iB * 4 + c];
        float4 accA = make_float4(0.f, 0.f, 0.f, 0.f);
        float4 accB = make_float4(0.f, 0.f, 0.f, 0.f);
        addp(accA, uA, r < cA);
        addp(accB, uB, r < cB);
        if (cA > 16) {                               // wave-uniform branch
            int r2 = 16 + r;
            int i2 = (r2 < cA) ? csr[begA + r2] : 0;
            addp(accA, g2[(size_t)i2 * 4 + c], r2 < cA);
            for (int rr = 32 + r; rr < cA; rr += 16)
                addp(accA, g2[(size_t)csr[begA + rr] * 4 + c], true);
        }
        if (cB > 16) {
            int r2 = 16 + r;
            int i2 = (r2 < cB) ? csr[begB + r2] : 0;
            addp(accB, g2[(size_t)i2 * 4 + c], r2 < cB);
            for (int rr = 32 + r; rr < cB; rr += 16)
                addp(accB, g2[(size_t)csr[begB + rr] * 4 + c], true);
        }
#pragma unroll
        for (int off = 4; off < 64; off <<= 1) {     // butterfly over rank bits
            accA.x += __shfl_xor(accA.x, off, 64);
            accA.y += __shfl_xor(accA.y, off, 64);
            accA.z += __shfl_xor(accA.z, off, 64);
            accA.w += __shfl_xor(accA.w, off, 64);
            accB.x += __shfl_xor(accB.x, off, 64);
            accB.y += __shfl_xor(accB.y, off, 64);
            accB.z += __shfl_xor(accB.z, off, 64);
            accB.w += __shfl_xor(accB.w, off, 64);
        }
        if (r == 0) {                                 // lanes 0..3 store node A
            const float di = dinv[nA];
            half4_t hv;
            hv[0] = (_Float16)fmaxf(fmaf(di, accA.x, bb.x), 0.f);
            hv[1] = (_Float16)fmaxf(fmaf(di, accA.y, bb.y), 0.f);
            hv[2] = (_Float16)fmaxf(fmaf(di, accA.z, bb.z), 0.f);
            hv[3] = (_Float16)fmaxf(fmaf(di, accA.w, bb.w), 0.f);
            a2[(size_t)nA * 4 + c] = *(uint2*)&hv;
        } else if (r == 1) {                          // lanes 4..7 store node B
            const float di = dinv[nB];
            half4_t hv;
            hv[0] = (_Float16)fmaxf(fmaf(di, accB.x, bb.x), 0.f);
            hv[1] = (_Float16)fmaxf(fmaf(di, accB.y, bb.y), 0.f);
            hv[2] = (_Float16)fmaxf(fmaf(di, accB.z, bb.z), 0.f);
            hv[3] = (_Float16)fmaxf(fmaf(di, accB.w, bb.w), 0.f);
            a2[(size_t)nB * 4 + c] = *(uint2*)&hv;
        }
    }
}

// ================= transform: agg tile -> MFMA @W -> dinv -> gfc_out (col layout) =============

__global__ __launch_bounds__(256, 8)
void tcol_kernel(const __half* __restrict__ agg, const float* __restrict__ W,
                 const float* __restrict__ dinv, __half* __restrict__ gfc_out) {
    __shared__ __align__(16) _Float16 tile[16 * 72];
    __shared__ __align__(16) _Float16 tile2[16 * 72];
    const int tid = threadIdx.x;
    const int lane = tid & 63, wid = tid >> 6;
    const int n0 = blockIdx.x * 16;
    const int row = tid >> 4, seg = tid & 15;
    const int p = seg >> 2, cc = seg & 3;
    uint2 v = ((const uint2*)agg)[((size_t)p * N_NODES + n0 + row) * 4 + cc];
    *(uint2*)(tile + row * 72 + seg * 4) = v;
    __syncthreads();

    const int kg = lane >> 4, n = lane & 15;
    half8_t B0, B1;
#pragma unroll
    for (int j = 0; j < 8; ++j) {
        B0[j] = (_Float16)W[(kg * 8 + j) * HID + wid * 16 + n];
        B1[j] = (_Float16)W[(32 + kg * 8 + j) * HID + wid * 16 + n];
    }
    half8_t A0 = *(const half8_t*)(tile + n * 72 + kg * 8);
    half8_t A1 = *(const half8_t*)(tile + n * 72 + 32 + kg * 8);
    f32x4_t c = {0.f, 0.f, 0.f, 0.f};
    c = __builtin_amdgcn_mfma_f32_16x16x32_f16(A0, B0, c, 0, 0, 0);
    c = __builtin_amdgcn_mfma_f32_16x16x32_f16(A1, B1, c, 0, 0, 0);

    const int q = lane >> 4;
#pragma unroll
    for (int rr = 0; rr < 4; ++rr)
        tile2[(q * 4 + rr) * 72 + wid * 16 + n] = (_Float16)(c[rr] * dinv[n0 + q * 4 + rr]);
    __syncthreads();
    uint2 o = *(const uint2*)(tile2 + row * 72 + seg * 4);
    ((uint2*)gfc_out)[((size_t)p * N_NODES + n0 + row) * 4 + cc] = o;
}

// ================= final transform: agg tile -> MFMA(Wm1) -> head -> sigmoid =================

__global__ __launch_bounds__(256, 8)
void tfinal_kernel(const __half* __restrict__ agg, const float* __restrict__ Wm1,
                   const float* __restrict__ bm1, const float* __restrict__ Wm2,
                   const float* __restrict__ bm2, float* __restrict__ out) {
    __shared__ __align__(16) _Float16 tile[16 * 72];
    __shared__ float redbuf[4][16];
    const int tid = threadIdx.x;
    const int lane = tid & 63, wid = tid >> 6;
    const int n0 = blockIdx.x * 16;
    const int row = tid >> 4, seg = tid & 15;
    const int p = seg >> 2, cc = seg & 3;
    uint2 v = ((const uint2*)agg)[((size_t)p * N_NODES + n0 + row) * 4 + cc];
    *(uint2*)(tile + row * 72 + seg * 4) = v;
    __syncthreads();

    const int kg = lane >> 4, n = lane & 15;
    half8_t B0, B1;
#pragma unroll
    for (int j = 0; j < 8; ++j) {
        B0[j] = (_Float16)Wm1[(kg * 8 + j) * HID + wid * 16 + n];
        B1[j] = (_Float16)Wm1[(32 + kg * 8 + j) * HID + wid * 16 + n];
    }
    half8_t A0 = *(const half8_t*)(tile + n * 72 + kg * 8);
    half8_t A1 = *(const half8_t*)(tile + n * 72 + 32 + kg * 8);
    f32x4_t c = {0.f, 0.f, 0.f, 0.f};
    c = __builtin_amdgcn_mfma_f32_16x16x32_f16(A0, B0, c, 0, 0, 0);
    c = __builtin_amdgcn_mfma_f32_16x16x32_f16(A1, B1, c, 0, 0, 0);

    const float bm1c = bm1[wid * 16 + n];
    const float wm2c = Wm2[wid * 16 + n];
    float part[4];
#pragma unroll
    for (int r = 0; r < 4; ++r) part[r] = fmaxf(c[r] + bm1c, 0.0f) * wm2c;
#pragma unroll
    for (int off = 1; off < 16; off <<= 1)
#pragma unroll
        for (int r = 0; r < 4; ++r) part[r] += __shfl_xor(part[r], off, 64);
    const int q = lane >> 4;
    if (n == 0) {
#pragma unroll
        for (int r = 0; r < 4; ++r) redbuf[wid][q * 4 + r] = part[r];
    }
    __syncthreads();
    if (tid < 16) {
        float s = redbuf[0][tid] + redbuf[1][tid] + redbuf[2][tid] + redbuf[3][tid];
        out[n0 + tid] = 1.0f / (1.0f + expf(-(s + bm2[0])));
    }
}

// ================= fused layer 1: 3-dim fp32 gather (linearity: agg before @W1) =================
// output written in col-blocked [4][N][16] layout for gcol.

__global__ __launch_bounds__(256, 8)
void fused_layer1_kernel(const float4* __restrict__ xd, const int* __restrict__ rowptr,
                         const int* __restrict__ csr, const float* __restrict__ dinv,
                         const float* __restrict__ b1, const float* __restrict__ W1,
                         const float* __restrict__ W2, __half* __restrict__ gfc_out) {
    __shared__ __align__(16) _Float16 tile[16 * 72];
    __shared__ __align__(16) _Float16 tile2[16 * 72];
    const int tid = threadIdx.x;
    const int lane = tid & 63, wid = tid >> 6;
    const int n0 = blockIdx.x * 16;

    // ---- 3-dim gather: node j = lane>>4 within wave, 16 lanes per node ----
    const int j = lane >> 4, p0 = lane & 15;
    const int l = wid * 4 + j;            // tile-local node 0..15
    const int node = n0 + l;
    const int beg = rowptr[node], end = rowptr[node + 1];
    float a0 = 0.f, a1 = 0.f, a2 = 0.f;
    for (int e = beg + p0; e < end; e += 16) {
        float4 v = xd[csr[e]];
        a0 += v.x; a1 += v.y; a2 += v.z;
    }
#pragma unroll
    for (int off = 1; off < 16; off <<= 1) {
        a0 += __shfl_xor(a0, off, 64);
        a1 += __shfl_xor(a1, off, 64);
        a2 += __shfl_xor(a2, off, 64);
    }
    const float dd = dinv[node];
    const float4 w0 = ((const float4*)W1)[p0];
    const float4 w1 = ((const float4*)(W1 + HID))[p0];
    const float4 w2 = ((const float4*)(W1 + 2 * HID))[p0];
    const float4 bb = ((const float4*)b1)[p0];
    half4_t hv;
    hv[0] = (_Float16)fmaxf(fmaf(dd, a0 * w0.x + a1 * w1.x + a2 * w2.x, bb.x), 0.f);
    hv[1] = (_Float16)fmaxf(fmaf(dd, a0 * w0.y + a1 * w1.y + a2 * w2.y, bb.y), 0.f);
    hv[2] = (_Float16)fmaxf(fmaf(dd, a0 * w0.z + a1 * w1.z + a2 * w2.z, bb.z), 0.f);
    hv[3] = (_Float16)fmaxf(fmaf(dd, a0 * w0.w + a1 * w1.w + a2 * w2.w, bb.w), 0.f);
    *(half4_t*)(tile + l * 72 + p0 * 4) = hv;
    __syncthreads();

    // ---- MFMA tail: gfc_out = dinv ⊙ (h1 @ W2) in col-blocked layout ----
    const int kg = lane >> 4, n = lane & 15;
    half8_t B0, B1;
#pragma unroll
    for (int jj = 0; jj < 8; ++jj) {
        B0[jj] = (_Float16)W2[(kg * 8 + jj) * HID + wid * 16 + n];
        B1[jj] = (_Float16)W2[(32 + kg * 8 + jj) * HID + wid * 16 + n];
    }
    half8_t A0 = *(const half8_t*)(tile + n * 72 + kg * 8);
    half8_t A1 = *(const half8_t*)(tile + n * 72 + 32 + kg * 8);
    f32x4_t c = {0.f, 0.f, 0.f, 0.f};
    c = __builtin_amdgcn_mfma_f32_16x16x32_f16(A0, B0, c, 0, 0, 0);
    c = __builtin_amdgcn_mfma_f32_16x16x32_f16(A1, B1, c, 0, 0, 0);

    const int q = lane >> 4;
#pragma unroll
    for (int r = 0; r < 4; ++r)
        tile2[(q * 4 + r) * 72 + wid * 16 + n] = (_Float16)(c[r] * dinv[n0 + q * 4 + r]);
    __syncthreads();
    const int row = tid >> 4, seg = tid & 15;
    uint2 v = *(const uint2*)(tile2 + row * 72 + seg * 4);
    ((uint2*)gfc_out)[((size_t)(seg >> 2) * N_NODES + n0 + row) * 4 + (seg & 3)] = v;
}

// ---------------- launch ----------------

extern "C" void kernel_launch(void* const* d_in, const int* in_sizes, int n_in,
                              void* d_out, int out_size, void* d_ws, size_t ws_size,
                              hipStream_t stream) {
    const float* x   = (const float*)d_in[0];
    const int*   ei  = (const int*)d_in[1];
    const float* W1  = (const float*)d_in[2];
    const float* b1  = (const float*)d_in[3];
    const float* W2  = (const float*)d_in[4];
    const float* b2  = (const float*)d_in[5];
    const float* W3  = (const float*)d_in[6];
    const float* b3  = (const float*)d_in[7];
    const float* Wm1 = (const float*)d_in[8];
    const float* bm1 = (const float*)d_in[9];
    const float* Wm2 = (const float*)d_in[10];
    const float* bm2 = (const float*)d_in[11];
    float* out = (float*)d_out;

    const int* src = ei;
    const int* dst = ei + N_EDGES;

    char* ws = (char*)d_ws;
    size_t off = 0;
    auto alloc = [&](size_t bytes) { size_t o = off; off = (off + bytes + 255) & ~(size_t)255; return (void*)(ws + o); };
    int*      rowptr = (int*)alloc(4ll * (N_NODES + 1));
    int*      gcur   = (int*)alloc(4ll * NBUCK);
    int*      bR0    = (int*)alloc(4ll * NBUCK);
    int*      csr    = (int*)alloc(4ll * (EP + 64));       // +64 pad (zeros)
    float*    dinv   = (float*)alloc(4ll * N_NODES);
    float4*   xd     = (float4*)alloc(16ll * N_NODES);     // dinv*x packed, 1.6 MB (L2-resident)
    __half*   gfc1   = (__half*)alloc(2ll * N_NODES * HID);   // col-blocked [4][N][16]
    __half*   agg2   = (__half*)alloc(2ll * N_NODES * HID);
    __half*   gfc2   = (__half*)alloc(2ll * N_NODES * HID);
    __half*   aggF   = (__half*)alloc(2ll * N_NODES * HID);
    unsigned* ebuf   = (unsigned*)alloc(4ll * (size_t)NBUCK * CAP);
    u64*      obuf   = (u64*)alloc(8ll * (size_t)NBUCK * OBSTRIDE);
    (void)ws_size;

    // --- CSR build v7 ---
    init_kernel<<<1, 512, 0, stream>>>(gcur, csr);
    scatter_kernel<<<NCHUNK, 1024, 0, stream>>>(src, dst, gcur, ebuf);
    bscan_kernel<<<1, 1024, 0, stream>>>(gcur, bR0);
    rankfill_kernel<<<NBUCK, 256, 0, stream>>>(ebuf, gcur, bR0, obuf, rowptr, csr, dinv, x, xd);

    // --- layer 1 (fused, 3-dim L2-resident gather) -> gfc1 (col layout) ---
    fused_layer1_kernel<<<NTILE, 256, 0, stream>>>(xd, rowptr, csr, dinv, b1, W1, W2, gfc1);

    // --- layer 2: column-pass gather (L2-resident) + MFMA transform ---
    gcol_kernel<<<4 * GT_TILES, 256, 0, stream>>>(gfc1, rowptr, csr, dinv, b2, agg2);
    tcol_kernel<<<NTILE, 256, 0, stream>>>(agg2, W3, dinv, gfc2);

    // --- layer 3 gather + MLP head ---
    gcol_kernel<<<4 * GT_TILES, 256, 0, stream>>>(gfc2, rowptr, csr, dinv, b3, aggF);
    tfinal_kernel<<<NTILE, 256, 0, stream>>>(aggF, Wm1, bm1, Wm2, bm2, out);
}